// Round 1
// baseline (284.980 us; speedup 1.0000x reference)
//
#include <hip/hip_runtime.h>
#include <math.h>

#define IMG_W 2048
#define IMG_H 2048
#define BATCH 8
#define MAX_PEAKS ((BATCH * IMG_H * IMG_W) / 8)   // 4194304
#define NWORDS (BATCH * IMG_H * IMG_W / 32)       // 1048576
#define LW 132                                    // LDS tile row stride (floats)

// ---------------------------------------------------------------------------
// K1: compute NMS mask, packed 32 pixels -> 1 uint32 word.
// Tile: 64 rows x 128 cols per block (+2 halo each side staged in LDS).
// Thread t: row r = t>>2 (0..63), col segment (t&3)*32 -> one word.
// mask bit = (s > 0) && (s >= max of 5x5 window)  [window contains s, so
// s >= window_max  <=>  s == maxfilter(s), exact fp equality semantics].
// ---------------------------------------------------------------------------
__device__ __forceinline__ void load36(const float* p, float* dst) {
    const float4* q = (const float4*)p;
#pragma unroll
    for (int m = 0; m < 9; ++m) {
        float4 v = q[m];
        dst[4 * m + 0] = v.x;
        dst[4 * m + 1] = v.y;
        dst[4 * m + 2] = v.z;
        dst[4 * m + 3] = v.w;
    }
}

__global__ __launch_bounds__(256) void nms_mask(const float* __restrict__ scores,
                                                unsigned* __restrict__ words) {
    __shared__ __align__(16) float tile[68 * LW];  // 35,904 B
    const int t = threadIdx.x;
    const int ctile = blockIdx.x;     // 0..15  (128-col tiles)
    const int rtile = blockIdx.y;     // 0..255 (64-row tiles across batch)
    const int img = rtile >> 5;       // 32 row-tiles per image
    const int r0 = (rtile & 31) << 6; // *64
    const int c0t = ctile << 7;       // *128
    const int imgBase = img * (IMG_H * IMG_W);

    // Stage 68 x 132 region: rows r0-2..r0+65, cols c0t-2..c0t+129 (-inf OOB)
    for (int i = t; i < 68 * LW; i += 256) {
        int rr = i / LW;
        int cc = i - rr * LW;
        int gr = r0 - 2 + rr;
        int gc = c0t - 2 + cc;
        float v = -INFINITY;
        if ((unsigned)gr < IMG_H && (unsigned)gc < IMG_W)
            v = scores[imgBase + gr * IMG_W + gc];
        tile[i] = v;
    }
    __syncthreads();

    const int r = t >> 2;           // output row within tile (tile row r+2)
    const int c0 = (t & 3) << 5;    // col segment start (LDS col c0 = j=-2)

    // Vertical max over window rows = tile rows r .. r+4, 36 cols (j=-2..33)
    float vmax[36], mid[36], tmp[36];
    load36(&tile[(r + 0) * LW + c0], vmax);
    load36(&tile[(r + 1) * LW + c0], tmp);
#pragma unroll
    for (int j = 0; j < 36; ++j) vmax[j] = fmaxf(vmax[j], tmp[j]);
    load36(&tile[(r + 2) * LW + c0], mid);   // the center row -- keep
#pragma unroll
    for (int j = 0; j < 36; ++j) vmax[j] = fmaxf(vmax[j], mid[j]);
    load36(&tile[(r + 3) * LW + c0], tmp);
#pragma unroll
    for (int j = 0; j < 36; ++j) vmax[j] = fmaxf(vmax[j], tmp[j]);
    load36(&tile[(r + 4) * LW + c0], tmp);
#pragma unroll
    for (int j = 0; j < 36; ++j) vmax[j] = fmaxf(vmax[j], tmp[j]);

    unsigned m = 0;
#pragma unroll
    for (int i = 0; i < 32; ++i) {
        float h5 = fmaxf(fmaxf(fmaxf(vmax[i], vmax[i + 1]),
                               fmaxf(vmax[i + 2], vmax[i + 3])),
                         vmax[i + 4]);
        float s = mid[i + 2];
        if (s > 0.0f && s >= h5) m |= (1u << i);
    }

    // word index in global p-order: p = img*H*W + (r0+r)*W + c0t + c0
    int gw = (img * IMG_H + r0 + r) * (IMG_W / 32) + (c0t >> 5) + (c0 >> 5);
    words[gw] = m;
}

// ---------------------------------------------------------------------------
// K2: per-block popcount sums (1024 blocks x 1024 words)
// ---------------------------------------------------------------------------
__global__ __launch_bounds__(256) void nms_blocksum(const unsigned* __restrict__ words,
                                                    unsigned* __restrict__ bsum) {
    __shared__ unsigned red[256];
    const int t = threadIdx.x;
    const int b = blockIdx.x;
    const uint4* p = (const uint4*)(words + b * 1024);
    uint4 q = p[t];
    unsigned s = __popc(q.x) + __popc(q.y) + __popc(q.z) + __popc(q.w);
    red[t] = s;
    __syncthreads();
#pragma unroll
    for (int d = 128; d > 0; d >>= 1) {
        if (t < d) red[t] += red[t + d];
        __syncthreads();
    }
    if (t == 0) bsum[b] = red[0];
}

// ---------------------------------------------------------------------------
// K3: single-block exclusive scan of 1024 block sums; base[1024] = total
// ---------------------------------------------------------------------------
__global__ __launch_bounds__(1024) void nms_scan(const unsigned* __restrict__ bsum,
                                                 unsigned* __restrict__ base) {
    __shared__ unsigned s[1024];
    const int t = threadIdx.x;
    unsigned v = bsum[t];
    s[t] = v;
    __syncthreads();
    for (int d = 1; d < 1024; d <<= 1) {
        unsigned u = (t >= d) ? s[t - d] : 0u;
        __syncthreads();
        s[t] += u;
        __syncthreads();
    }
    base[t] = s[t] - v;                    // exclusive prefix
    if (t == 1023) base[1024] = s[1023];   // total count
}

// ---------------------------------------------------------------------------
// K4: ordered compaction. Block b handles words [b*1024, b*1024+1024).
// Within block: scan per-thread popcounts (4 words/thread, word-ordered),
// then emit (h, w) per set bit, LSB-first => exact ascending-p order.
// ---------------------------------------------------------------------------
__global__ __launch_bounds__(256) void nms_compact(const unsigned* __restrict__ words,
                                                   const unsigned* __restrict__ base,
                                                   int* __restrict__ out) {
    __shared__ unsigned red[256];
    const int t = threadIdx.x;
    const int b = blockIdx.x;
    const uint4* p = (const uint4*)(words + b * 1024);
    uint4 q = p[t];
    unsigned wv[4] = {q.x, q.y, q.z, q.w};
    unsigned tsum = __popc(wv[0]) + __popc(wv[1]) + __popc(wv[2]) + __popc(wv[3]);
    red[t] = tsum;
    __syncthreads();
    // Hillis-Steele inclusive scan over 256 thread sums
    for (int d = 1; d < 256; d <<= 1) {
        unsigned u = (t >= d) ? red[t - d] : 0u;
        __syncthreads();
        red[t] += u;
        __syncthreads();
    }
    unsigned off = base[b] + red[t] - tsum;  // exclusive offset for this thread
    const unsigned gword0 = (unsigned)b * 1024u + (unsigned)t * 4u;
#pragma unroll
    for (int wi = 0; wi < 4; ++wi) {
        unsigned m = wv[wi];
        unsigned pbase = (gword0 + wi) << 5;
        while (m) {
            int bit = __builtin_ctz(m);
            m &= m - 1;
            unsigned ppix = pbase + (unsigned)bit;
            int hh = (int)((ppix >> 11) & 2047u);
            int ww = (int)(ppix & 2047u);
            if (off < (unsigned)MAX_PEAKS) {
                out[off] = hh;
                out[MAX_PEAKS + off] = ww;
            }
            ++off;
        }
    }
}

// ---------------------------------------------------------------------------
// K5: fill entries >= total with -1 in both coordinate rows
// ---------------------------------------------------------------------------
__global__ __launch_bounds__(256) void nms_fill(const unsigned* __restrict__ base,
                                                int* __restrict__ out) {
    unsigned total = base[1024];
    unsigned k = blockIdx.x * 256u + threadIdx.x;
    if (k < (unsigned)MAX_PEAKS && k >= total) {
        out[k] = -1;
        out[MAX_PEAKS + k] = -1;
    }
}

extern "C" void kernel_launch(void* const* d_in, const int* in_sizes, int n_in,
                              void* d_out, int out_size, void* d_ws, size_t ws_size,
                              hipStream_t stream) {
    const float* scores = (const float*)d_in[0];
    int* out = (int*)d_out;
    unsigned* words = (unsigned*)d_ws;            // 1,048,576 words (4 MB)
    unsigned* bsum = words + NWORDS;              // 1024
    unsigned* base = bsum + 1024;                 // 1025 (incl. total)

    nms_mask<<<dim3(16, 256), 256, 0, stream>>>(scores, words);
    nms_blocksum<<<1024, 256, 0, stream>>>(words, bsum);
    nms_scan<<<1, 1024, 0, stream>>>(bsum, base);
    nms_compact<<<1024, 256, 0, stream>>>(words, base, out);
    nms_fill<<<MAX_PEAKS / 256, 256, 0, stream>>>(base, out);
}

// Round 2
// 216.663 us; speedup vs baseline: 1.3153x; 1.3153x over previous
//
#include <hip/hip_runtime.h>
#include <math.h>

#define IMG_W 2048
#define IMG_H 2048
#define BATCH 8
#define MAX_PEAKS ((BATCH * IMG_H * IMG_W) / 8)   // 4194304
#define NWORDS (BATCH * IMG_H * IMG_W / 32)       // 1048576
#define ROWSW 32                                  // rows per wave
#define NFILL 2048                                // tail-fill blocks

// ---------------------------------------------------------------------------
// K1: register-ring NMS mask. No LDS tile. Each wave owns a 256-col strip
// (lane = 4 cols, float4 loads); 8-deep register ring of rows gives the
// vertical 5-max; horizontal +-2 halo via shfl_up/down with edge lanes
// (0,63) carrying 2 extra halo columns from one predicated float4 load.
// Bits packed across 8-lane groups via shfl_xor OR-reduce; per-16-row
// popcounts atomically added to bsum (replaces the old blocksum kernel).
// mask bit = (s > 0) && (s >= 5x5 window max)  ==  (s == maxfilter) & (s > 0)
// ---------------------------------------------------------------------------
__global__ __launch_bounds__(256) void nms_mask(const float* __restrict__ scores,
                                                unsigned* __restrict__ words,
                                                unsigned* __restrict__ bsum) {
    const int t = threadIdx.x;
    const int lane = t & 63;
    const int wv = t >> 6;            // wave in block: 0..3
    const int b = blockIdx.x;         // 0..1023
    const int img = b >> 7;           // 8 images x 128 blocks
    const int rem = b & 127;
    const int strip = rem >> 4;       // 8 column strips of 256
    const int chunk = rem & 15;       // 16 row chunks of 128
    const int r0 = chunk * 128 + wv * ROWSW;
    const int c0 = strip * 256;
    const int cl = c0 + lane * 4;
    const long imgBase = (long)img * (IMG_H * IMG_W);

    const float* colp = scores + imgBase + cl;
    const bool isL = (lane == 0), isR = (lane == 63);
    const int ecol = isL ? (c0 - 4) : (c0 + 256);
    const bool evalid = (isL || isR) && ((unsigned)ecol < IMG_W);
    const float* ecolp = scores + imgBase + ecol;

    const float NEG = -INFINITY;
    float4 ring[8];
    float2 ringE[8];

    // warm-up: rows r0-2 .. r0+1 -> slots 0..3
#pragma unroll
    for (int m = 0; m < 4; ++m) {
        int gr = r0 - 2 + m;
        float4 nv = make_float4(NEG, NEG, NEG, NEG);
        float2 ne = make_float2(NEG, NEG);
        if ((unsigned)gr < IMG_H) {
            nv = *(const float4*)(colp + (long)gr * IMG_W);
            if (evalid) {
                float4 ev = *(const float4*)(ecolp + (long)gr * IMG_W);
                ne = isL ? make_float2(ev.z, ev.w) : make_float2(ev.x, ev.y);
            }
        }
        ring[m] = nv;
        ringE[m] = ne;
    }

    unsigned cnt = 0;
    const int shamt = (lane & 7) * 4;
    long wIdx = (long)(img * IMG_H + r0) * (IMG_W / 32) + strip * 8 + (lane >> 3);
    const int cb0 = (img * IMG_H + r0) >> 4;   // compact-block (16-row) index

#pragma unroll 1
    for (int i8 = 0; i8 < ROWSW / 8; ++i8) {
#pragma unroll
        for (int u = 0; u < 8; ++u) {
            const int gr = r0 + i8 * 8 + u + 2;   // row being loaded
            float4 nv = make_float4(NEG, NEG, NEG, NEG);
            float2 ne = make_float2(NEG, NEG);
            if ((unsigned)gr < IMG_H) {           // wave-uniform branch
                nv = *(const float4*)(colp + (long)gr * IMG_W);
                if (evalid) {
                    float4 ev = *(const float4*)(ecolp + (long)gr * IMG_W);
                    ne = isL ? make_float2(ev.z, ev.w) : make_float2(ev.x, ev.y);
                }
            }
            ring[(u + 4) & 7] = nv;
            ringE[(u + 4) & 7] = ne;

            const float4 w0 = ring[u & 7];
            const float4 w1 = ring[(u + 1) & 7];
            const float4 mid = ring[(u + 2) & 7];
            const float4 w3 = ring[(u + 3) & 7];
            const float4 w4 = ring[(u + 4) & 7];
            // vertical 5-max per column
            float vmx = fmaxf(fmaxf(fmaxf(w0.x, w1.x), fmaxf(mid.x, w3.x)), w4.x);
            float vmy = fmaxf(fmaxf(fmaxf(w0.y, w1.y), fmaxf(mid.y, w3.y)), w4.y);
            float vmz = fmaxf(fmaxf(fmaxf(w0.z, w1.z), fmaxf(mid.z, w3.z)), w4.z);
            float vmw = fmaxf(fmaxf(fmaxf(w0.w, w1.w), fmaxf(mid.w, w3.w)), w4.w);
            const float2 e0 = ringE[u & 7];
            const float2 e1 = ringE[(u + 1) & 7];
            const float2 e2 = ringE[(u + 2) & 7];
            const float2 e3 = ringE[(u + 3) & 7];
            const float2 e4 = ringE[(u + 4) & 7];
            float vex = fmaxf(fmaxf(fmaxf(e0.x, e1.x), fmaxf(e2.x, e3.x)), e4.x);
            float vey = fmaxf(fmaxf(fmaxf(e0.y, e1.y), fmaxf(e2.y, e3.y)), e4.y);

            // horizontal halo: left neighbor cols (z,w), right neighbor (x,y)
            float A = __shfl_up(vmz, 1);
            float B = __shfl_up(vmw, 1);
            float C = __shfl_down(vmx, 1);
            float D = __shfl_down(vmy, 1);
            if (isL) { A = vex; B = vey; }
            if (isR) { C = vex; D = vey; }

            float t12 = fmaxf(vmy, vmz);
            float m02 = fmaxf(vmx, t12);        // max cols 0..2
            float m03 = fmaxf(m02, vmw);        // max cols 0..3
            float m13 = fmaxf(t12, vmw);        // max cols 1..3
            float h0 = fmaxf(fmaxf(A, B), m02);
            float h1 = fmaxf(B, m03);
            float h2 = fmaxf(m03, C);
            float h3 = fmaxf(m13, fmaxf(C, D));

            unsigned nib = 0;
            nib |= (mid.x > 0.0f && mid.x >= h0) ? 1u : 0u;
            nib |= (mid.y > 0.0f && mid.y >= h1) ? 2u : 0u;
            nib |= (mid.z > 0.0f && mid.z >= h2) ? 4u : 0u;
            nib |= (mid.w > 0.0f && mid.w >= h3) ? 8u : 0u;

            unsigned wd = nib << shamt;
            wd |= __shfl_xor(wd, 1);
            wd |= __shfl_xor(wd, 2);
            wd |= __shfl_xor(wd, 4);
            if ((lane & 7) == 0) {
                words[wIdx] = wd;
                cnt += __popc(wd);
            }
            wIdx += IMG_W / 32;
        }
        if (i8 & 1) {   // flush per 16 rows -> compact-block sums
            unsigned s = cnt;
            s += __shfl_xor(s, 1);
            s += __shfl_xor(s, 2);
            s += __shfl_xor(s, 4);
            s += __shfl_xor(s, 8);
            s += __shfl_xor(s, 16);
            s += __shfl_xor(s, 32);
            if (lane == 0) atomicAdd(&bsum[cb0 + (i8 >> 1)], s);
            cnt = 0;
        }
    }
}

// ---------------------------------------------------------------------------
// K2: exclusive scan of 1024 block sums (256 threads, wave-scan, 1 barrier);
// base[1024] = total
// ---------------------------------------------------------------------------
__global__ __launch_bounds__(256) void nms_scan(const unsigned* __restrict__ bsum,
                                                unsigned* __restrict__ base) {
    __shared__ unsigned wtot[4];
    const int t = threadIdx.x;
    const int lane = t & 63, wid = t >> 6;
    uint4 v = ((const uint4*)bsum)[t];
    unsigned s0 = v.x, s1 = v.x + v.y, s2 = s1 + v.z, ts = s2 + v.w;
    unsigned sc = ts;
#pragma unroll
    for (int d = 1; d < 64; d <<= 1) {
        unsigned o = __shfl_up(sc, d);
        if (lane >= d) sc += o;
    }
    if (lane == 63) wtot[wid] = sc;
    __syncthreads();
    unsigned wpre = 0;
#pragma unroll
    for (int k = 0; k < 4; ++k) wpre += (k < wid) ? wtot[k] : 0u;
    unsigned excl = wpre + sc - ts;
    ((uint4*)base)[t] = make_uint4(excl, excl + s0, excl + s1, excl + s2);
    if (t == 255) base[1024] = wpre + sc;
}

// ---------------------------------------------------------------------------
// K3: ordered compaction (blocks 0..1023) + -1 tail fill (blocks 1024..)
// ---------------------------------------------------------------------------
__global__ __launch_bounds__(256) void nms_compact(const unsigned* __restrict__ words,
                                                   const unsigned* __restrict__ base,
                                                   int* __restrict__ out) {
    const int t = threadIdx.x;
    const int b = blockIdx.x;
    if (b < 1024) {
        __shared__ unsigned wq[4];
        const int lane = t & 63, wid = t >> 6;
        uint4 q = ((const uint4*)(words + b * 1024))[t];
        unsigned wv[4] = {q.x, q.y, q.z, q.w};
        unsigned tsum = __popc(wv[0]) + __popc(wv[1]) + __popc(wv[2]) + __popc(wv[3]);
        unsigned sc = tsum;
#pragma unroll
        for (int d = 1; d < 64; d <<= 1) {
            unsigned o = __shfl_up(sc, d);
            if (lane >= d) sc += o;
        }
        if (lane == 63) wq[wid] = sc;
        __syncthreads();
        unsigned wpre = 0;
#pragma unroll
        for (int k = 0; k < 4; ++k) wpre += (k < wid) ? wq[k] : 0u;
        unsigned off = base[b] + wpre + sc - tsum;

        const unsigned gword0 = (unsigned)b * 1024u + (unsigned)t * 4u;
#pragma unroll
        for (int wi = 0; wi < 4; ++wi) {
            unsigned m = wv[wi];
            unsigned pbase = (gword0 + wi) << 5;
            while (m) {
                int bit = __builtin_ctz(m);
                m &= m - 1;
                unsigned ppix = pbase + (unsigned)bit;
                int hh = (int)((ppix >> 11) & 2047u);
                int ww = (int)(ppix & 2047u);
                if (off < (unsigned)MAX_PEAKS) {
                    out[off] = hh;
                    out[MAX_PEAKS + off] = ww;
                }
                ++off;
            }
        }
    } else {
        unsigned total = base[1024];
        if (total > (unsigned)MAX_PEAKS) total = MAX_PEAKS;
        unsigned tail = (unsigned)MAX_PEAKS - total;
        unsigned fb = (unsigned)(b - 1024);
        unsigned per = (tail + NFILL - 1) / NFILL;
        unsigned s = total + fb * per;
        unsigned e = s + per;
        if (e > (unsigned)MAX_PEAKS) e = MAX_PEAKS;
        for (unsigned k = s + t; k < e; k += 256) {
            out[k] = -1;
            out[MAX_PEAKS + k] = -1;
        }
    }
}

extern "C" void kernel_launch(void* const* d_in, const int* in_sizes, int n_in,
                              void* d_out, int out_size, void* d_ws, size_t ws_size,
                              hipStream_t stream) {
    const float* scores = (const float*)d_in[0];
    int* out = (int*)d_out;
    unsigned* words = (unsigned*)d_ws;            // 1,048,576 words (4 MB)
    unsigned* bsum = words + NWORDS;              // 1024 (16B aligned)
    unsigned* base = bsum + 1024;                 // 1025 (incl. total)

    hipMemsetAsync(bsum, 0, 1024 * sizeof(unsigned), stream);
    nms_mask<<<1024, 256, 0, stream>>>(scores, words, bsum);
    nms_scan<<<1, 256, 0, stream>>>(bsum, base);
    nms_compact<<<1024 + NFILL, 256, 0, stream>>>(words, base, out);
}

// Round 3
// 213.691 us; speedup vs baseline: 1.3336x; 1.0139x over previous
//
#include <hip/hip_runtime.h>
#include <math.h>

#define IMG_W 2048
#define IMG_H 2048
#define BATCH 8
#define MAX_PEAKS ((BATCH * IMG_H * IMG_W) / 8)   // 4194304
#define NWORDS (BATCH * IMG_H * IMG_W / 32)       // 1048576
#define ROWSW 32                                  // rows per wave
#define NFILL 2048                                // tail-fill blocks

// ---------------------------------------------------------------------------
// K1: register-ring NMS mask, fully branch-free inner loop.
// Wave owns a 256-col strip x 32 rows; lane = 4 cols (float4 loads).
// Vertical 5-max via 8-deep register ring; horizontal +-2 halo via
// shfl_up/down. Edge halo: ONE unconditional 64-lane load per row where
// lanes 0..31 all read the left-edge float4 and lanes 32..63 the right-edge
// float4 (2 distinct 16B segments -> 32B traffic, no divergent branch).
// Out-of-range rows/cols: address clamped, value forced to -inf via select.
// Per-(16-row, strip) popcounts stored to unique bsum2 slots (no atomics,
// no memset needed).
// mask bit = (s > 0) && (s >= 5x5 window max)
// ---------------------------------------------------------------------------
__device__ __forceinline__ void load_row(const float* __restrict__ colp,
                                         const float* __restrict__ ecolp,
                                         int gr, bool leftHalf, bool evalid,
                                         float4& nv, float2& ne) {
    const float NEG = -INFINITY;
    int rc = gr < 0 ? 0 : (gr > IMG_H - 1 ? IMG_H - 1 : gr);
    size_t off = (size_t)rc * IMG_W;
    float4 v = *(const float4*)(colp + off);    // unconditional
    float4 ev = *(const float4*)(ecolp + off);  // unconditional, 2 segs/wave
    bool rv = ((unsigned)gr < IMG_H);
    bool ok = rv && evalid;
    float ex = leftHalf ? ev.z : ev.x;
    float ey = leftHalf ? ev.w : ev.y;
    nv.x = rv ? v.x : NEG;
    nv.y = rv ? v.y : NEG;
    nv.z = rv ? v.z : NEG;
    nv.w = rv ? v.w : NEG;
    ne.x = ok ? ex : NEG;
    ne.y = ok ? ey : NEG;
}

__global__ __launch_bounds__(256, 4) void nms_mask(const float* __restrict__ scores,
                                                   unsigned* __restrict__ words,
                                                   unsigned* __restrict__ bsum2) {
    const int t = threadIdx.x;
    const int lane = t & 63;
    const int wv = t >> 6;            // wave in block: 0..3
    const int b = blockIdx.x;         // 0..1023
    const int img = b >> 7;           // 8 images x 128 blocks
    const int rem = b & 127;
    const int strip = rem >> 4;       // 8 column strips of 256
    const int chunk = rem & 15;       // 16 row chunks of 128
    const int r0 = chunk * 128 + wv * ROWSW;
    const int c0 = strip * 256;
    const int cl = c0 + lane * 4;
    const size_t imgBase = (size_t)img * (IMG_H * IMG_W);

    const float* colp = scores + imgBase + cl;
    const bool leftHalf = (lane < 32);
    const bool isL = (lane == 0), isR = (lane == 63);
    int ecol = leftHalf ? (c0 - 4) : (c0 + 256);
    const bool evalid = ((unsigned)ecol < IMG_W);
    int ecolC = evalid ? ecol : c0;                 // clamped valid address
    const float* ecolp = scores + imgBase + ecolC;

    float4 ring[8];
    float2 ringE[8];

    // warm-up: rows r0-2 .. r0+1 -> slots 0..3
#pragma unroll
    for (int m = 0; m < 4; ++m)
        load_row(colp, ecolp, r0 - 2 + m, leftHalf, evalid, ring[m], ringE[m]);

    unsigned cnt = 0;
    const int shamt = (lane & 7) * 4;
    size_t wIdx = (size_t)(img * IMG_H + r0) * (IMG_W / 32) + strip * 8 + (lane >> 3);
    const int cb0 = (img * IMG_H + r0) >> 4;   // compact-block (16-row) index

#pragma unroll 1
    for (int i8 = 0; i8 < ROWSW / 8; ++i8) {
#pragma unroll
        for (int u = 0; u < 8; ++u) {
            const int gr = r0 + i8 * 8 + u + 2;   // row being loaded
            load_row(colp, ecolp, gr, leftHalf, evalid,
                     ring[(u + 4) & 7], ringE[(u + 4) & 7]);

            const float4 w0 = ring[u & 7];
            const float4 w1 = ring[(u + 1) & 7];
            const float4 mid = ring[(u + 2) & 7];
            const float4 w3 = ring[(u + 3) & 7];
            const float4 w4 = ring[(u + 4) & 7];
            // vertical 5-max per column
            float vmx = fmaxf(fmaxf(fmaxf(w0.x, w1.x), fmaxf(mid.x, w3.x)), w4.x);
            float vmy = fmaxf(fmaxf(fmaxf(w0.y, w1.y), fmaxf(mid.y, w3.y)), w4.y);
            float vmz = fmaxf(fmaxf(fmaxf(w0.z, w1.z), fmaxf(mid.z, w3.z)), w4.z);
            float vmw = fmaxf(fmaxf(fmaxf(w0.w, w1.w), fmaxf(mid.w, w3.w)), w4.w);
            const float2 e0 = ringE[u & 7];
            const float2 e1 = ringE[(u + 1) & 7];
            const float2 e2 = ringE[(u + 2) & 7];
            const float2 e3 = ringE[(u + 3) & 7];
            const float2 e4 = ringE[(u + 4) & 7];
            float vex = fmaxf(fmaxf(fmaxf(e0.x, e1.x), fmaxf(e2.x, e3.x)), e4.x);
            float vey = fmaxf(fmaxf(fmaxf(e0.y, e1.y), fmaxf(e2.y, e3.y)), e4.y);

            // horizontal halo: left neighbor cols (z,w), right neighbor (x,y)
            float A = __shfl_up(vmz, 1);
            float B = __shfl_up(vmw, 1);
            float C = __shfl_down(vmx, 1);
            float D = __shfl_down(vmy, 1);
            if (isL) { A = vex; B = vey; }
            if (isR) { C = vex; D = vey; }

            float t12 = fmaxf(vmy, vmz);
            float m02 = fmaxf(vmx, t12);        // max cols 0..2
            float m03 = fmaxf(m02, vmw);        // max cols 0..3
            float m13 = fmaxf(t12, vmw);        // max cols 1..3
            float h0 = fmaxf(fmaxf(A, B), m02);
            float h1 = fmaxf(B, m03);
            float h2 = fmaxf(m03, C);
            float h3 = fmaxf(m13, fmaxf(C, D));

            unsigned nib = 0;
            nib |= (mid.x > 0.0f && mid.x >= h0) ? 1u : 0u;
            nib |= (mid.y > 0.0f && mid.y >= h1) ? 2u : 0u;
            nib |= (mid.z > 0.0f && mid.z >= h2) ? 4u : 0u;
            nib |= (mid.w > 0.0f && mid.w >= h3) ? 8u : 0u;

            unsigned wd = nib << shamt;
            wd |= __shfl_xor(wd, 1);
            wd |= __shfl_xor(wd, 2);
            wd |= __shfl_xor(wd, 4);
            if ((lane & 7) == 0) {
                words[wIdx] = wd;
                cnt += __popc(wd);
            }
            wIdx += IMG_W / 32;
        }
        if (i8 & 1) {   // flush per 16 rows -> per-(chunk,strip) sum slot
            unsigned s = cnt;
            s += __shfl_xor(s, 1);
            s += __shfl_xor(s, 2);
            s += __shfl_xor(s, 4);
            s += __shfl_xor(s, 8);
            s += __shfl_xor(s, 16);
            s += __shfl_xor(s, 32);
            if (lane == 0) bsum2[(cb0 + (i8 >> 1)) * 8 + strip] = s;
            cnt = 0;
        }
    }
}

// ---------------------------------------------------------------------------
// K2: scan. Reduce 8 strip-sums per 16-row chunk (8192 slots -> 1024 cbs),
// exclusive scan, base[1024] = total. One 256-thread block.
// ---------------------------------------------------------------------------
__global__ __launch_bounds__(256) void nms_scan(const unsigned* __restrict__ bsum2,
                                                unsigned* __restrict__ base) {
    __shared__ unsigned wtot[4];
    const int t = threadIdx.x;
    const int lane = t & 63, wid = t >> 6;
    const uint4* p = (const uint4*)(bsum2 + t * 32);   // 4 cbs x 8 slots
    unsigned c[4];
#pragma unroll
    for (int i = 0; i < 4; ++i) {
        uint4 a = p[2 * i], bq = p[2 * i + 1];
        c[i] = a.x + a.y + a.z + a.w + bq.x + bq.y + bq.z + bq.w;
    }
    unsigned s0 = c[0], s1 = s0 + c[1], s2 = s1 + c[2], ts = s2 + c[3];
    unsigned sc = ts;
#pragma unroll
    for (int d = 1; d < 64; d <<= 1) {
        unsigned o = __shfl_up(sc, d);
        if (lane >= d) sc += o;
    }
    if (lane == 63) wtot[wid] = sc;
    __syncthreads();
    unsigned wpre = 0;
#pragma unroll
    for (int k = 0; k < 4; ++k) wpre += (k < wid) ? wtot[k] : 0u;
    unsigned excl = wpre + sc - ts;
    ((uint4*)base)[t] = make_uint4(excl, excl + s0, excl + s1, excl + s2);
    if (t == 255) base[1024] = wpre + sc;
}

// ---------------------------------------------------------------------------
// K3: ordered compaction (blocks 0..1023) + -1 tail fill (blocks 1024..)
// ---------------------------------------------------------------------------
__global__ __launch_bounds__(256) void nms_compact(const unsigned* __restrict__ words,
                                                   const unsigned* __restrict__ base,
                                                   int* __restrict__ out) {
    const int t = threadIdx.x;
    const int b = blockIdx.x;
    if (b < 1024) {
        __shared__ unsigned wq[4];
        const int lane = t & 63, wid = t >> 6;
        uint4 q = ((const uint4*)(words + b * 1024))[t];
        unsigned wv[4] = {q.x, q.y, q.z, q.w};
        unsigned tsum = __popc(wv[0]) + __popc(wv[1]) + __popc(wv[2]) + __popc(wv[3]);
        unsigned sc = tsum;
#pragma unroll
        for (int d = 1; d < 64; d <<= 1) {
            unsigned o = __shfl_up(sc, d);
            if (lane >= d) sc += o;
        }
        if (lane == 63) wq[wid] = sc;
        __syncthreads();
        unsigned wpre = 0;
#pragma unroll
        for (int k = 0; k < 4; ++k) wpre += (k < wid) ? wq[k] : 0u;
        unsigned off = base[b] + wpre + sc - tsum;

        const unsigned gword0 = (unsigned)b * 1024u + (unsigned)t * 4u;
#pragma unroll
        for (int wi = 0; wi < 4; ++wi) {
            unsigned m = wv[wi];
            unsigned pbase = (gword0 + wi) << 5;
            while (m) {
                int bit = __builtin_ctz(m);
                m &= m - 1;
                unsigned ppix = pbase + (unsigned)bit;
                int hh = (int)((ppix >> 11) & 2047u);
                int ww = (int)(ppix & 2047u);
                if (off < (unsigned)MAX_PEAKS) {
                    out[off] = hh;
                    out[MAX_PEAKS + off] = ww;
                }
                ++off;
            }
        }
    } else {
        unsigned total = base[1024];
        if (total > (unsigned)MAX_PEAKS) total = MAX_PEAKS;
        unsigned tail = (unsigned)MAX_PEAKS - total;
        unsigned fb = (unsigned)(b - 1024);
        unsigned per = (tail + NFILL - 1) / NFILL;
        unsigned s = total + fb * per;
        unsigned e = s + per;
        if (e > (unsigned)MAX_PEAKS) e = MAX_PEAKS;
        for (unsigned k = s + t; k < e; k += 256) {
            out[k] = -1;
            out[MAX_PEAKS + k] = -1;
        }
    }
}

extern "C" void kernel_launch(void* const* d_in, const int* in_sizes, int n_in,
                              void* d_out, int out_size, void* d_ws, size_t ws_size,
                              hipStream_t stream) {
    const float* scores = (const float*)d_in[0];
    int* out = (int*)d_out;
    unsigned* words = (unsigned*)d_ws;            // 1,048,576 words (4 MB)
    unsigned* bsum2 = words + NWORDS;             // 8192 per-(chunk,strip) sums
    unsigned* base = bsum2 + 8192;                // 1025 (incl. total)

    nms_mask<<<1024, 256, 0, stream>>>(scores, words, bsum2);
    nms_scan<<<1, 256, 0, stream>>>(bsum2, base);
    nms_compact<<<1024 + NFILL, 256, 0, stream>>>(words, base, out);
}